// Round 2
// baseline (1711.689 us; speedup 1.0000x reference)
//
#include <hip/hip_runtime.h>

#define BSH 7                    // nodes per bucket = 128
#define BNODES 128
#define CHUNK 16384              // edges per scatter block

static __device__ __forceinline__ float frelu(float v){ return v > 0.f ? v : 0.f; }

// ---------------------------------------------------------------------------
// int64 vs int32 edge-index detection (node ids < N << 2^31, so int64 high
// words are all zero; int32 data has real indices in odd slots).
__global__ void detect_kernel(const unsigned int* __restrict__ e, int* __restrict__ flag){
    __shared__ int odd_nz;
    if (threadIdx.x == 0) odd_nz = 0;
    __syncthreads();
    int local = 0;
    for (int i = threadIdx.x; i < 512; i += blockDim.x){
        if (e[2*i + 1] != 0u) local = 1;
    }
    if (local) atomicOr(&odd_nz, 1);
    __syncthreads();
    if (threadIdx.x == 0) *flag = (odd_nz == 0) ? 1 : 0;
}

static __device__ __forceinline__ int load_idx(const void* eidx, int flg, long long pos){
    if (flg) return (int)((const long long*)eidx)[pos];
    return ((const int*)eidx)[pos];
}

// in-degree count (edges only; self-loop added analytically in dis)
__global__ void count_kernel(const void* __restrict__ eidx, const int* __restrict__ flag,
                             int* __restrict__ deg, int E){
    int i = blockIdx.x * blockDim.x + threadIdx.x;
    if (i >= E) return;
    int dst = load_idx(eidx, *flag, (long long)E + i);
    atomicAdd(&deg[dst], 1);
}

__global__ void dis_kernel(const int* __restrict__ deg, float* __restrict__ dis, int N){
    int i = blockIdx.x * blockDim.x + threadIdx.x;
    if (i < N) dis[i] = rsqrtf((float)(deg[i] + 1));   // +1 = self loop
}

// bucket offsets from per-node degrees; single block, nbuck <= 1024
__global__ void bucket_scan_kernel(const int* __restrict__ deg, int* __restrict__ boff,
                                   int* __restrict__ bcursor, int N, int nbuck){
    __shared__ int sums[1024];
    int tid = threadIdx.x;
    int s = 0;
    if (tid < nbuck){
        int base = tid << BSH;
        int end  = min(base + BNODES, N);
        for (int i = base; i < end; ++i) s += deg[i];
    }
    sums[tid] = s;
    __syncthreads();
    for (int off = 1; off < 1024; off <<= 1){
        int t = (tid >= off) ? sums[tid - off] : 0;
        __syncthreads();
        sums[tid] += t;
        __syncthreads();
    }
    if (tid < nbuck){
        int pfx = sums[tid] - s;      // exclusive prefix
        boff[tid]    = pfx;
        bcursor[tid] = pfx;
    }
    if (tid == 0) boff[nbuck] = sums[1023];
}

// binned scatter: bpairs[pos] = (src,dst) grouped by dst-bucket.
// Per block: LDS histogram + rank, one global atomic per (block,bucket)
// reserving a contiguous range -> ~21-entry (168B) contiguous write runs.
__global__ __launch_bounds__(256) void binned_scatter_kernel(
        const void* __restrict__ eidx, const int* __restrict__ flag,
        int* __restrict__ bcursor, int2* __restrict__ bpairs, int E, int nbuck){
    __shared__ int hist[800];
    __shared__ int base[800];
    __shared__ unsigned short rank[CHUNK];
    int tid = threadIdx.x;
    int flg = *flag;
    long long c0 = (long long)blockIdx.x * CHUNK;
    int cnt = (int)min((long long)CHUNK, (long long)E - c0);
    for (int i = tid; i < nbuck; i += 256) hist[i] = 0;
    __syncthreads();
    for (int i = tid; i < cnt; i += 256){
        int dst = load_idx(eidx, flg, (long long)E + c0 + i);
        rank[i] = (unsigned short)atomicAdd(&hist[dst >> BSH], 1);
    }
    __syncthreads();
    for (int i = tid; i < nbuck; i += 256){
        int h = hist[i];
        base[i] = h ? atomicAdd(&bcursor[i], h) : 0;
    }
    __syncthreads();
    for (int i = tid; i < cnt; i += 256){
        int src = load_idx(eidx, flg, c0 + i);
        int dst = load_idx(eidx, flg, (long long)E + c0 + i);
        bpairs[base[dst >> BSH] + (int)rank[i]] = make_int2(src, dst);
    }
}

// h1s[i][c] = (x[i,:] @ W1[:,c]) * dis[i]    x:[N,256] W1:[256,32]
__global__ __launch_bounds__(256) void gemm1_kernel(const float* __restrict__ x,
        const float* __restrict__ W1, const float* __restrict__ dis,
        float* __restrict__ h1s, int N){
    int lane = threadIdx.x & 31;
    int grp  = threadIdx.x >> 5;
    int row0 = (blockIdx.x * 8 + grp) * 8;
    float acc[8];
#pragma unroll
    for (int r = 0; r < 8; ++r) acc[r] = 0.f;
    for (int c = 0; c < 4; ++c){
        int k0 = c * 64;
        float w[64];
#pragma unroll
        for (int kk = 0; kk < 64; ++kk) w[kk] = W1[(k0 + kk) * 32 + lane];
#pragma unroll
        for (int r = 0; r < 8; ++r){
            int row = row0 + r;
            if (row < N){
                const float4* xr = (const float4*)(x + row * 256 + k0);
#pragma unroll
                for (int q = 0; q < 16; ++q){
                    float4 xv = xr[q];
                    acc[r] += xv.x * w[q*4+0] + xv.y * w[q*4+1]
                            + xv.z * w[q*4+2] + xv.w * w[q*4+3];
                }
            }
        }
    }
#pragma unroll
    for (int r = 0; r < 8; ++r){
        int row = row0 + r;
        if (row < N) h1s[row * 32 + lane] = acc[r] * dis[row];
    }
}

// bucketed aggregation: one block per bucket; LDS fp32 accumulator.
// out_i = f( (sum_{j->i} hs_j + hs_i) * dis_i )
// mode 1: r = relu(v + b) * dis   (layer-1 output, pre-scaled for layer 2)
// mode 0: r = v                    (layer-2 pre-GEMM activations)
__global__ __launch_bounds__(256) void agg_lds_kernel(
        const float* __restrict__ hs, const int2* __restrict__ bpairs,
        const int* __restrict__ boff, const float* __restrict__ dis,
        const float* __restrict__ bias, float* __restrict__ outb,
        int N, int mode){
    __shared__ float acc[BNODES * 32];          // 16 KB
    int b = blockIdx.x;
    int nodeBase = b << BSH;
    int nNodes = min(BNODES, N - nodeBase);
    int tid = threadIdx.x;
    for (int i = tid; i < (nNodes << 5); i += 256) acc[i] = 0.f;
    __syncthreads();

    int beg = boff[b], end = boff[b + 1];
    int feat = tid & 31;
    int slot = tid >> 5;                        // 0..7
    const int U = 8;                            // edges in flight per slot
    for (int k = beg; k < end; k += 8 * U){
        int2  p[U];
        float v[U];
#pragma unroll
        for (int u = 0; u < U; ++u){
            int e = k + slot * U + u;
            p[u] = (e < end) ? bpairs[e] : make_int2(-1, nodeBase);
        }
#pragma unroll
        for (int u = 0; u < U; ++u)
            v[u] = (p[u].x >= 0) ? hs[(long long)p[u].x * 32 + feat] : 0.f;
#pragma unroll
        for (int u = 0; u < U; ++u)
            if (p[u].x >= 0)
                atomicAdd(&acc[((p[u].y - nodeBase) << 5) + feat], v[u]);
    }
    __syncthreads();

    for (int i = tid; i < nNodes * 8; i += 256){
        int n  = i >> 3;
        int fq = i & 7;
        int node = nodeBase + n;
        float4 a = *(const float4*)&acc[(n << 5) + fq * 4];
        float4 s = ((const float4*)hs)[node * 8 + fq];
        float  d = dis[node];
        float4 r;
        r.x = (a.x + s.x) * d; r.y = (a.y + s.y) * d;
        r.z = (a.z + s.z) * d; r.w = (a.w + s.w) * d;
        if (mode == 1){
            float4 bb = ((const float4*)bias)[fq];
            r.x = frelu(r.x + bb.x) * d; r.y = frelu(r.y + bb.y) * d;
            r.z = frelu(r.z + bb.z) * d; r.w = frelu(r.w + bb.w) * d;
        }
        ((float4*)outb)[node * 8 + fq] = r;
    }
}

// out[i][c] = a2[i,:] @ W2[:,c] + b2[c]    a2:[N,32] W2:[32,128]
__global__ __launch_bounds__(128) void gemm2_kernel(const float* __restrict__ a2,
        const float* __restrict__ W2, const float* __restrict__ b2,
        float* __restrict__ out, int N){
    int c = threadIdx.x;
    int base = blockIdx.x * 32;
    float w[32];
#pragma unroll
    for (int k = 0; k < 32; ++k) w[k] = W2[k * 128 + c];
    float bias = b2[c];
    for (int r = 0; r < 32; ++r){
        int row = base + r;
        if (row >= N) break;
        const float4* ar = (const float4*)(a2 + row * 32);
        float acc = bias;
#pragma unroll
        for (int p = 0; p < 8; ++p){
            float4 av = ar[p];
            acc += av.x * w[p*4+0] + av.y * w[p*4+1]
                 + av.z * w[p*4+2] + av.w * w[p*4+3];
        }
        out[row * 128 + c] = acc;
    }
}

extern "C" void kernel_launch(void* const* d_in, const int* in_sizes, int n_in,
                              void* d_out, int out_size, void* d_ws, size_t ws_size,
                              hipStream_t stream){
    const float* x  = (const float*)d_in[0];
    const void*  ei = d_in[1];
    const float* W1 = (const float*)d_in[2];
    const float* b1 = (const float*)d_in[3];
    const float* W2 = (const float*)d_in[4];
    const float* b2 = (const float*)d_in[5];
    float* out = (float*)d_out;

    const int N = in_sizes[0] / 256;   // 100000
    const int E = in_sizes[1] / 2;     // 3200000
    const int nbuck = (N + BNODES - 1) >> BSH;

    char* ws = (char*)d_ws;
    size_t off = 0;
    auto alloc = [&](size_t bytes) -> char* {
        char* p = ws + off;
        off = (off + bytes + 255) & ~(size_t)255;
        return p;
    };
    int*   flag    = (int*)  alloc(4);
    int*   deg     = (int*)  alloc((size_t)N * 4);
    int*   boff    = (int*)  alloc((size_t)(nbuck + 1) * 4);
    int*   bcursor = (int*)  alloc((size_t)nbuck * 4);
    float* dis     = (float*)alloc((size_t)N * 4);
    int2*  bpairs  = (int2*) alloc((size_t)E * 8);
    float* h1s     = (float*)alloc((size_t)N * 32 * 4);
    float* h2s     = (float*)alloc((size_t)N * 32 * 4);
    float* a2      = h1s;   // h1s dead after first aggregation

    hipMemsetAsync(deg, 0, (size_t)N * 4, stream);

    detect_kernel      <<<1, 256, 0, stream>>>((const unsigned int*)ei, flag);
    count_kernel       <<<(E + 255) / 256, 256, 0, stream>>>(ei, flag, deg, E);
    dis_kernel         <<<(N + 255) / 256, 256, 0, stream>>>(deg, dis, N);
    bucket_scan_kernel <<<1, 1024, 0, stream>>>(deg, boff, bcursor, N, nbuck);
    binned_scatter_kernel<<<(E + CHUNK - 1) / CHUNK, 256, 0, stream>>>(
        ei, flag, bcursor, bpairs, E, nbuck);

    gemm1_kernel   <<<(N + 63) / 64, 256, 0, stream>>>(x, W1, dis, h1s, N);
    agg_lds_kernel <<<nbuck, 256, 0, stream>>>(h1s, bpairs, boff, dis, b1, h2s, N, 1);
    agg_lds_kernel <<<nbuck, 256, 0, stream>>>(h2s, bpairs, boff, dis, b2, a2, N, 0);
    gemm2_kernel   <<<(N + 31) / 32, 128, 0, stream>>>(a2, W2, b2, out, N);
}

// Round 3
// 1525.239 us; speedup vs baseline: 1.1222x; 1.1222x over previous
//
#include <hip/hip_runtime.h>

#define BSH 7                    // nodes per bucket = 128
#define BNODES 128
#define CHUNK 8192               // edges per scatter block
#define MAXBUCK 800

static __device__ __forceinline__ float frelu(float v){ return v > 0.f ? v : 0.f; }

// ---------------------------------------------------------------------------
// int64 vs int32 edge-index detection (node ids < N << 2^31, so int64 high
// words are all zero; int32 data has real indices in odd slots).
__global__ void detect_kernel(const unsigned int* __restrict__ e, int* __restrict__ flag){
    __shared__ int odd_nz;
    if (threadIdx.x == 0) odd_nz = 0;
    __syncthreads();
    int local = 0;
    for (int i = threadIdx.x; i < 512; i += blockDim.x){
        if (e[2*i + 1] != 0u) local = 1;
    }
    if (local) atomicOr(&odd_nz, 1);
    __syncthreads();
    if (threadIdx.x == 0) *flag = (odd_nz == 0) ? 1 : 0;
}

static __device__ __forceinline__ int load_idx(const void* eidx, int flg, long long pos){
    if (flg) return (int)((const long long*)eidx)[pos];
    return ((const int*)eidx)[pos];
}

// in-degree count (edges only; self-loop added analytically in dis)
__global__ void count_kernel(const void* __restrict__ eidx, const int* __restrict__ flag,
                             int* __restrict__ deg, int E){
    int i = blockIdx.x * blockDim.x + threadIdx.x;
    if (i >= E) return;
    int dst = load_idx(eidx, *flag, (long long)E + i);
    atomicAdd(&deg[dst], 1);
}

__global__ void dis_kernel(const int* __restrict__ deg, float* __restrict__ dis, int N){
    int i = blockIdx.x * blockDim.x + threadIdx.x;
    if (i < N) dis[i] = rsqrtf((float)(deg[i] + 1));   // +1 = self loop
}

// bucket offsets from per-node degrees; single block, nbuck <= 1024
__global__ void bucket_scan_kernel(const int* __restrict__ deg, int* __restrict__ boff,
                                   int* __restrict__ bcursor, int N, int nbuck){
    __shared__ int sums[1024];
    int tid = threadIdx.x;
    int s = 0;
    if (tid < nbuck){
        int base = tid << BSH;
        int end  = min(base + BNODES, N);
        for (int i = base; i < end; ++i) s += deg[i];
    }
    sums[tid] = s;
    __syncthreads();
    for (int off = 1; off < 1024; off <<= 1){
        int t = (tid >= off) ? sums[tid - off] : 0;
        __syncthreads();
        sums[tid] += t;
        __syncthreads();
    }
    if (tid < nbuck){
        int pfx = sums[tid] - s;      // exclusive prefix
        boff[tid]    = pfx;
        bcursor[tid] = pfx;
    }
    if (tid == 0) boff[nbuck] = sums[1023];
}

// binned scatter: bpk[pos] = (local_dst<<24)|src grouped by dst-bucket.
// Per block: LDS histogram + rank, one global atomic per (block,bucket)
// reserving a contiguous range -> contiguous write runs, 4B per edge.
__global__ __launch_bounds__(256) void binned_scatter_kernel(
        const void* __restrict__ eidx, const int* __restrict__ flag,
        int* __restrict__ bcursor, unsigned int* __restrict__ bpk, int E, int nbuck){
    __shared__ int hist[MAXBUCK];
    __shared__ int base[MAXBUCK];
    __shared__ unsigned short rank[CHUNK];
    int tid = threadIdx.x;
    int flg = *flag;
    long long c0 = (long long)blockIdx.x * CHUNK;
    int cnt = (int)min((long long)CHUNK, (long long)E - c0);
    for (int i = tid; i < nbuck; i += 256) hist[i] = 0;
    __syncthreads();
    for (int i = tid; i < cnt; i += 256){
        int dst = load_idx(eidx, flg, (long long)E + c0 + i);
        rank[i] = (unsigned short)atomicAdd(&hist[dst >> BSH], 1);
    }
    __syncthreads();
    for (int i = tid; i < nbuck; i += 256){
        int h = hist[i];
        base[i] = h ? atomicAdd(&bcursor[i], h) : 0;
    }
    __syncthreads();
    for (int i = tid; i < cnt; i += 256){
        int src = load_idx(eidx, flg, c0 + i);
        int dst = load_idx(eidx, flg, (long long)E + c0 + i);
        unsigned int local = (unsigned int)(dst & (BNODES - 1));
        bpk[base[dst >> BSH] + (int)rank[i]] = (local << 24) | (unsigned int)src;
    }
}

// h1s[i][c] = (x[i,:] @ W1[:,c]) * dis[i]    x:[N,256] W1:[256,32]
__global__ __launch_bounds__(256) void gemm1_kernel(const float* __restrict__ x,
        const float* __restrict__ W1, const float* __restrict__ dis,
        float* __restrict__ h1s, int N){
    int lane = threadIdx.x & 31;
    int grp  = threadIdx.x >> 5;
    int row0 = (blockIdx.x * 8 + grp) * 8;
    float acc[8];
#pragma unroll
    for (int r = 0; r < 8; ++r) acc[r] = 0.f;
    for (int c = 0; c < 4; ++c){
        int k0 = c * 64;
        float w[64];
#pragma unroll
        for (int kk = 0; kk < 64; ++kk) w[kk] = W1[(k0 + kk) * 32 + lane];
#pragma unroll
        for (int r = 0; r < 8; ++r){
            int row = row0 + r;
            if (row < N){
                const float4* xr = (const float4*)(x + row * 256 + k0);
#pragma unroll
                for (int q = 0; q < 16; ++q){
                    float4 xv = xr[q];
                    acc[r] += xv.x * w[q*4+0] + xv.y * w[q*4+1]
                            + xv.z * w[q*4+2] + xv.w * w[q*4+3];
                }
            }
        }
    }
#pragma unroll
    for (int r = 0; r < 8; ++r){
        int row = row0 + r;
        if (row < N) h1s[row * 32 + lane] = acc[r] * dis[row];
    }
}

// split-bucket aggregation: grid (nbuck, split); each block accumulates a
// slice of the bucket's edges into a 16 KB LDS slab, then streams the slab
// to its per-split partial buffer (no atomics, no global memset needed).
__global__ __launch_bounds__(256) void agg_split_kernel(
        const float* __restrict__ hs, const unsigned int* __restrict__ bpk,
        const int* __restrict__ boff, float* __restrict__ partial,
        int N, int split){
    __shared__ float acc[BNODES * 32];          // 16 KB
    int b = blockIdx.x;
    int s = blockIdx.y;
    int tid = threadIdx.x;
    int nodeBase = b << BSH;
    int nNodes = min(BNODES, N - nodeBase);
    for (int i = tid; i < (nNodes << 5); i += 256) acc[i] = 0.f;
    __syncthreads();

    int beg = boff[b], end = boff[b + 1], len = end - beg;
    int s0 = beg + (int)((long long)len * s / split);
    int s1 = beg + (int)((long long)len * (s + 1) / split);

    int feat = tid & 31;
    int slot = tid >> 5;                        // 0..7
    const int U = 8;                            // edges in flight per slot
    for (int k = s0; k < s1; k += 8 * U){
        unsigned int p[U];
        float v[U];
        int ok[U];
#pragma unroll
        for (int u = 0; u < U; ++u){
            int e = k + slot * U + u;
            ok[u] = (e < s1);
            p[u] = ok[u] ? bpk[e] : 0u;
        }
#pragma unroll
        for (int u = 0; u < U; ++u)
            v[u] = ok[u] ? hs[(size_t)(p[u] & 0xFFFFFFu) * 32 + feat] : 0.f;
#pragma unroll
        for (int u = 0; u < U; ++u)
            if (ok[u])
                atomicAdd(&acc[((p[u] >> 24) << 5) + feat], v[u]);
    }
    __syncthreads();

    float* dst = partial + ((size_t)s * N + nodeBase) * 32;
    for (int i = tid; i < (nNodes << 3); i += 256)
        ((float4*)dst)[i] = *(const float4*)&acc[i << 2];
}

// epilogue: sum split partials + self-loop, scale, bias/relu
// mode 1: r = relu((agg+self)*d + b) * d   (layer-1 out, pre-scaled for L2)
// mode 0: r = (agg+self)*d                 (layer-2 pre-GEMM activations)
__global__ __launch_bounds__(256) void epilogue_kernel(
        const float* __restrict__ partial, const float* __restrict__ hs,
        const float* __restrict__ dis, const float* __restrict__ bias,
        float* __restrict__ outb, int N, int split, int mode){
    int gid = blockIdx.x * blockDim.x + threadIdx.x;
    if (gid >= N * 8) return;
    int node = gid >> 3;
    int fq   = gid & 7;
    float4 a = make_float4(0.f, 0.f, 0.f, 0.f);
    for (int s = 0; s < split; ++s){
        float4 p = ((const float4*)partial)[(size_t)s * N * 8 + gid];
        a.x += p.x; a.y += p.y; a.z += p.z; a.w += p.w;
    }
    float4 sv = ((const float4*)hs)[gid];
    float  d  = dis[node];
    float4 r;
    r.x = (a.x + sv.x) * d; r.y = (a.y + sv.y) * d;
    r.z = (a.z + sv.z) * d; r.w = (a.w + sv.w) * d;
    if (mode == 1){
        float4 bb = ((const float4*)bias)[fq];
        r.x = frelu(r.x + bb.x) * d; r.y = frelu(r.y + bb.y) * d;
        r.z = frelu(r.z + bb.z) * d; r.w = frelu(r.w + bb.w) * d;
    }
    ((float4*)outb)[gid] = r;
}

// out[i][c] = a2[i,:] @ W2[:,c] + b2[c]    a2:[N,32] W2:[32,128]
__global__ __launch_bounds__(128) void gemm2_kernel(const float* __restrict__ a2,
        const float* __restrict__ W2, const float* __restrict__ b2,
        float* __restrict__ out, int N){
    int c = threadIdx.x;
    int base = blockIdx.x * 32;
    float w[32];
#pragma unroll
    for (int k = 0; k < 32; ++k) w[k] = W2[k * 128 + c];
    float bias = b2[c];
    for (int r = 0; r < 32; ++r){
        int row = base + r;
        if (row >= N) break;
        const float4* ar = (const float4*)(a2 + row * 32);
        float acc = bias;
#pragma unroll
        for (int p = 0; p < 8; ++p){
            float4 av = ar[p];
            acc += av.x * w[p*4+0] + av.y * w[p*4+1]
                 + av.z * w[p*4+2] + av.w * w[p*4+3];
        }
        out[row * 128 + c] = acc;
    }
}

extern "C" void kernel_launch(void* const* d_in, const int* in_sizes, int n_in,
                              void* d_out, int out_size, void* d_ws, size_t ws_size,
                              hipStream_t stream){
    const float* x  = (const float*)d_in[0];
    const void*  ei = d_in[1];
    const float* W1 = (const float*)d_in[2];
    const float* b1 = (const float*)d_in[3];
    const float* W2 = (const float*)d_in[4];
    const float* b2 = (const float*)d_in[5];
    float* out = (float*)d_out;

    const int N = in_sizes[0] / 256;   // 100000
    const int E = in_sizes[1] / 2;     // 3200000
    const int nbuck = (N + BNODES - 1) >> BSH;

    // workspace layout (256B-aligned slabs)
    size_t fixed = 0;
    auto sz = [&](size_t bytes){ size_t o = fixed; fixed = (fixed + bytes + 255) & ~(size_t)255; return o; };
    size_t o_flag = sz(4);
    size_t o_deg  = sz((size_t)N * 4);
    size_t o_boff = sz((size_t)(nbuck + 1) * 4);
    size_t o_bcur = sz((size_t)nbuck * 4);
    size_t o_dis  = sz((size_t)N * 4);
    size_t o_bpk  = sz((size_t)E * 4);
    size_t o_h1s  = sz((size_t)N * 32 * 4);
    size_t o_h2s  = sz((size_t)N * 32 * 4);
    size_t slab   = (size_t)N * 32 * 4;
    int split = 4;
    while (split > 1 && fixed + (size_t)split * slab > ws_size) split >>= 1;
    size_t o_part = sz((size_t)split * slab);

    char* ws = (char*)d_ws;
    int*   flag    = (int*)  (ws + o_flag);
    int*   deg     = (int*)  (ws + o_deg);
    int*   boff    = (int*)  (ws + o_boff);
    int*   bcursor = (int*)  (ws + o_bcur);
    float* dis     = (float*)(ws + o_dis);
    unsigned int* bpk = (unsigned int*)(ws + o_bpk);
    float* h1s     = (float*)(ws + o_h1s);
    float* h2s     = (float*)(ws + o_h2s);
    float* partial = (float*)(ws + o_part);
    float* a2      = h1s;   // h1s dead after epilogue-1

    hipMemsetAsync(deg, 0, (size_t)N * 4, stream);

    detect_kernel      <<<1, 256, 0, stream>>>((const unsigned int*)ei, flag);
    count_kernel       <<<(E + 255) / 256, 256, 0, stream>>>(ei, flag, deg, E);
    dis_kernel         <<<(N + 255) / 256, 256, 0, stream>>>(deg, dis, N);
    bucket_scan_kernel <<<1, 1024, 0, stream>>>(deg, boff, bcursor, N, nbuck);
    binned_scatter_kernel<<<(E + CHUNK - 1) / CHUNK, 256, 0, stream>>>(
        ei, flag, bcursor, bpk, E, nbuck);

    gemm1_kernel    <<<(N + 63) / 64, 256, 0, stream>>>(x, W1, dis, h1s, N);

    dim3 agrid(nbuck, split);
    agg_split_kernel<<<agrid, 256, 0, stream>>>(h1s, bpk, boff, partial, N, split);
    epilogue_kernel <<<(N * 8 + 255) / 256, 256, 0, stream>>>(
        partial, h1s, dis, b1, h2s, N, split, 1);

    agg_split_kernel<<<agrid, 256, 0, stream>>>(h2s, bpk, boff, partial, N, split);
    epilogue_kernel <<<(N * 8 + 255) / 256, 256, 0, stream>>>(
        partial, h2s, dis, b2, a2, N, split, 0);

    gemm2_kernel    <<<(N + 31) / 32, 128, 0, stream>>>(a2, W2, b2, out, N);
}